// Round 3
// baseline (513.593 us; speedup 1.0000x reference)
//
#include <hip/hip_runtime.h>
#include <hip/hip_bf16.h>

// ObjectAttentionBlock on MI355X, round 3.
// KEY FIX vs r2: the reference's output dtype is FP32 (all jnp.float32, no
// casts) -> d_out is float*. r2 wrote bf16 (half the buffer, wrong encoding):
// absmax 1.2969 == max|ref| over the never-written half. Final GEMM now
// stores f32. Internal pipeline stays bf16-MFMA with f32 accumulation.

typedef __bf16 bf16x8 __attribute__((ext_vector_type(8)));
typedef float f32x4 __attribute__((ext_vector_type(4)));
typedef unsigned short u16x8 __attribute__((ext_vector_type(8)));

#define MFMA_16x16x32(a, b, c) __builtin_amdgcn_mfma_f32_16x16x32_bf16((a), (b), (c), 0, 0, 0)

__device__ __forceinline__ unsigned short f2bf(float f) {
  union { float f; unsigned u; } x; x.f = f;
  unsigned r = (x.u + 0x7FFFu + ((x.u >> 16) & 1u)) >> 16;  // RNE
  return (unsigned short)r;
}

// ---------------- elementwise cast (weights) ----------------
__global__ __launch_bounds__(256) void cast_f32_bf16(const float* __restrict__ s,
                                                     unsigned short* __restrict__ d, int n) {
  int i = blockIdx.x * 256 + threadIdx.x;
  if (i < n) d[i] = f2bf(s[i]);
}

// ---------------- transpose + cast: x [B][512][HW] f32 -> xT [B][HW][512] bf16 ----------------
__global__ __launch_bounds__(256) void transpose_cast_x(const float* __restrict__ x,
                                                        unsigned short* __restrict__ xT) {
  const int HW = 16384, C = 512;
  __shared__ float tile[64][65];
  const int b = blockIdx.z;
  const int p0 = blockIdx.x * 64, c0 = blockIdx.y * 64;
  const int t = threadIdx.x;
  // load: 64 ch-rows x 64 pixels = 1024 float4 chunks
#pragma unroll
  for (int i = 0; i < 4; i++) {
    int chunk = t + i * 256;            // 0..1023 -> 64 rows x 16 float4
    int cl = chunk >> 4, q = chunk & 15;
    float4 v = *(const float4*)(x + ((size_t)b * C + c0 + cl) * HW + p0 + q * 4);
    tile[cl][q * 4 + 0] = v.x; tile[cl][q * 4 + 1] = v.y;
    tile[cl][q * 4 + 2] = v.z; tile[cl][q * 4 + 3] = v.w;
  }
  __syncthreads();
  // store: 64 pixels x 4 groups of 16 ch = 256 items (one per thread)
  {
    int pl = t >> 2, g = t & 3;
    u16x8 o0, o1;
#pragma unroll
    for (int j = 0; j < 8; j++) {
      o0[j] = f2bf(tile[g * 16 + j][pl]);
      o1[j] = f2bf(tile[g * 16 + 8 + j][pl]);
    }
    unsigned short* dst = xT + ((size_t)b * HW + p0 + pl) * C + c0 + g * 16;
    *(u16x8*)dst = o0;
    *(u16x8*)(dst + 8) = o1;
  }
}

// ---------------- key/value kernel (fp32 math, tiny) ----------------
// keyT [B][160][256]: keyT[b][p][kc]; Vv [B][256][160]: Vv[b][kc][p].
// p in [150,160) gets bias-only finite values; masked in attention.
__global__ __launch_bounds__(256) void kv_kernel(
    const float* __restrict__ proxy,
    const float* __restrict__ w_fo1, const float* __restrict__ b_fo1,
    const float* __restrict__ w_fo2, const float* __restrict__ b_fo2,
    const float* __restrict__ w_fd, const float* __restrict__ b_fd,
    unsigned short* __restrict__ keyT, unsigned short* __restrict__ Vv) {
  __shared__ float cols[512][8];
  __shared__ float k1s[256][8];
  const int b = blockIdx.y;
  const int p0 = blockIdx.x * 8;      // 20 chunks cover p 0..159
  const int t = threadIdx.x;
#pragma unroll
  for (int i = 0; i < 8; i++) {
    int idx = t + i * 256;            // 0..2047 = 512 ch x 4 float2
    int c = idx >> 2, q = idx & 3;
    int p = p0 + q * 2;
    float2 v = make_float2(0.f, 0.f);
    if (p < 150) v = *(const float2*)(proxy + ((size_t)b * 512 + c) * 150 + p);  // p even, p+1<=149
    cols[c][q * 2 + 0] = v.x;
    cols[c][q * 2 + 1] = v.y;
  }
  __syncthreads();
  float accV[8], accK[8];
  {
    float bv = b_fd[t], bk = b_fo1[t];
#pragma unroll
    for (int px = 0; px < 8; px++) { accV[px] = bv; accK[px] = bk; }
  }
#define KV_FMA(j, wv_, wk_)                                      \
  { float4 ca = *(const float4*)&cols[c + j][0];                 \
    float4 cb = *(const float4*)&cols[c + j][4];                 \
    accV[0] += wv_ * ca.x; accV[1] += wv_ * ca.y;                \
    accV[2] += wv_ * ca.z; accV[3] += wv_ * ca.w;                \
    accV[4] += wv_ * cb.x; accV[5] += wv_ * cb.y;                \
    accV[6] += wv_ * cb.z; accV[7] += wv_ * cb.w;                \
    accK[0] += wk_ * ca.x; accK[1] += wk_ * ca.y;                \
    accK[2] += wk_ * ca.z; accK[3] += wk_ * ca.w;                \
    accK[4] += wk_ * cb.x; accK[5] += wk_ * cb.y;                \
    accK[6] += wk_ * cb.z; accK[7] += wk_ * cb.w; }
  for (int c = 0; c < 512; c += 4) {
    float4 wv4 = *(const float4*)(w_fd + (size_t)t * 512 + c);
    float4 wk4 = *(const float4*)(w_fo1 + (size_t)t * 512 + c);
    KV_FMA(0, wv4.x, wk4.x)
    KV_FMA(1, wv4.y, wk4.y)
    KV_FMA(2, wv4.z, wk4.z)
    KV_FMA(3, wv4.w, wk4.w)
  }
#pragma unroll
  for (int px = 0; px < 8; px++) {
    Vv[((size_t)b * 256 + t) * 160 + p0 + px] = f2bf(fmaxf(accV[px], 0.f));
    k1s[t][px] = fmaxf(accK[px], 0.f);
  }
  __syncthreads();
  float accY[8];
  {
    float by = b_fo2[t];
#pragma unroll
    for (int px = 0; px < 8; px++) accY[px] = by;
  }
#define KV_FMA2(j, wy_)                                          \
  { float4 ca = *(const float4*)&k1s[c + j][0];                  \
    float4 cb = *(const float4*)&k1s[c + j][4];                  \
    accY[0] += wy_ * ca.x; accY[1] += wy_ * ca.y;                \
    accY[2] += wy_ * ca.z; accY[3] += wy_ * ca.w;                \
    accY[4] += wy_ * cb.x; accY[5] += wy_ * cb.y;                \
    accY[6] += wy_ * cb.z; accY[7] += wy_ * cb.w; }
  for (int c = 0; c < 256; c += 4) {
    float4 wy4 = *(const float4*)(w_fo2 + (size_t)t * 256 + c);
    KV_FMA2(0, wy4.x)
    KV_FMA2(1, wy4.y)
    KV_FMA2(2, wy4.z)
    KV_FMA2(3, wy4.w)
  }
#pragma unroll
  for (int px = 0; px < 8; px++)
    keyT[((size_t)b * 160 + p0 + px) * 256 + t] = f2bf(fmaxf(accY[px], 0.f));
}

// ---------------- generic bf16 GEMM: C = relu(A @ Bt^T + bias) ----------------
// A [M][K], Bt [N][K] row-major bf16. Output bf16 (OUTF32=0) or f32 (OUTF32=1).
// m97-style: 128x128 tile, BK=64, global_load_lds(16B), 4 waves x 4x4 frags.
template <int BIAS_ROW, int OUTF32>
__global__ __launch_bounds__(256) void gemm_bt_relu(
    const unsigned short* __restrict__ A, const unsigned short* __restrict__ Bt,
    const float* __restrict__ bias, void* __restrict__ Cout,
    int M, int N, int K, long long sA, long long sB, long long sC) {
  __shared__ unsigned short As[128 * 64];
  __shared__ unsigned short Bs[128 * 64];
  const int b = blockIdx.z;
  const int m0 = blockIdx.x * 128, n0 = blockIdx.y * 128;
  const int tid = threadIdx.x;
  const int w = tid >> 6, l = tid & 63;
  const int lr = l & 15, lg = l >> 4;
  const int wm = (w >> 1) * 64, wn = (w & 1) * 64;
  const unsigned short* Ab = A + (size_t)b * sA + (size_t)m0 * K;
  const unsigned short* Btb = Bt + (size_t)b * sB + (size_t)n0 * K;
  const f32x4 zero = {0.f, 0.f, 0.f, 0.f};
  f32x4 acc[4][4];
#pragma unroll
  for (int m = 0; m < 4; m++)
#pragma unroll
    for (int n = 0; n < 4; n++) acc[m][n] = zero;

  const int srow = w * 32 + (l >> 3);   // staging row per lane
  const int scol = (l & 7) * 8;         // staging col (bf16 elems)
  for (int kt = 0; kt < K; kt += 64) {
    __syncthreads();                    // LDS safe to overwrite
#pragma unroll
    for (int i = 0; i < 4; i++) {
      __builtin_amdgcn_global_load_lds(
          (__attribute__((address_space(1))) void*)(Ab + (size_t)(srow + i * 8) * K + kt + scol),
          (__attribute__((address_space(3))) void*)(As + (w * 32 + i * 8) * 64), 16, 0, 0);
      __builtin_amdgcn_global_load_lds(
          (__attribute__((address_space(1))) void*)(Btb + (size_t)(srow + i * 8) * K + kt + scol),
          (__attribute__((address_space(3))) void*)(Bs + (w * 32 + i * 8) * 64), 16, 0, 0);
    }
    __syncthreads();                    // compiler drains vmcnt before barrier
#pragma unroll
    for (int ks = 0; ks < 2; ks++) {
      bf16x8 aF[4], bF[4];
#pragma unroll
      for (int m = 0; m < 4; m++)
        aF[m] = *(const bf16x8*)(As + (wm + m * 16 + lr) * 64 + ks * 32 + lg * 8);
#pragma unroll
      for (int n = 0; n < 4; n++)
        bF[n] = *(const bf16x8*)(Bs + (wn + n * 16 + lr) * 64 + ks * 32 + lg * 8);
#pragma unroll
      for (int m = 0; m < 4; m++)
#pragma unroll
        for (int n = 0; n < 4; n++) acc[m][n] = MFMA_16x16x32(aF[m], bF[n], acc[m][n]);
    }
  }
#pragma unroll
  for (int m = 0; m < 4; m++) {
#pragma unroll
    for (int n = 0; n < 4; n++) {
      const int col = n0 + wn + n * 16 + lr;
      const float bc = BIAS_ROW ? 0.f : bias[col];
#pragma unroll
      for (int r = 0; r < 4; r++) {
        const int row = m0 + wm + m * 16 + lg * 4 + r;
        float v = acc[m][n][r] + (BIAS_ROW ? bias[row] : bc);
        v = fmaxf(v, 0.f);
        if (OUTF32)
          ((float*)Cout)[(size_t)b * sC + (size_t)row * N + col] = v;
        else
          ((unsigned short*)Cout)[(size_t)b * sC + (size_t)row * N + col] = f2bf(v);
      }
    }
  }
}

// ---------------- fused attention: ctxT = softmax(Q Kt^T /16) @ V ----------------
// Q [B][HW][256], Kt [B][160][256] (rows>=150 masked), Vv [B][256][160]
// (cols>=150 finite, P=0 there), ctxT [B][HW][256]. Block = 128 pixels, 4 waves.
__global__ __launch_bounds__(256) void attn_kernel(
    const unsigned short* __restrict__ Q, const unsigned short* __restrict__ Kt,
    const unsigned short* __restrict__ Vv, unsigned short* __restrict__ ctxT) {
  const int HW = 16384;
  __shared__ unsigned short Pls[128 * 168];   // stride 168: 336B rows, 16B-aligned
  const int b = blockIdx.y;
  const int pix0 = blockIdx.x * 128;
  const int tid = threadIdx.x;
  const int w = tid >> 6, l = tid & 63;
  const int lr = l & 15, lg = l >> 4;
  const unsigned short* Qb = Q + ((size_t)b * HW + pix0 + w * 32) * 256;
  const unsigned short* Kb = Kt + (size_t)b * 160 * 256;
  const unsigned short* Vb = Vv + (size_t)b * 256 * 160;
  const f32x4 zero = {0.f, 0.f, 0.f, 0.f};

  // S = Q @ K^T : wave owns 32 pixel-rows x 160 key-cols
  f32x4 acc[2][10];
#pragma unroll
  for (int m = 0; m < 2; m++)
#pragma unroll
    for (int n = 0; n < 10; n++) acc[m][n] = zero;
#pragma unroll 2
  for (int ks = 0; ks < 8; ks++) {
    bf16x8 aF[2];
#pragma unroll
    for (int m = 0; m < 2; m++)
      aF[m] = *(const bf16x8*)(Qb + (size_t)(m * 16 + lr) * 256 + ks * 32 + lg * 8);
#pragma unroll
    for (int n = 0; n < 10; n++) {
      bf16x8 bF = *(const bf16x8*)(Kb + (size_t)(n * 16 + lr) * 256 + ks * 32 + lg * 8);
      acc[0][n] = MFMA_16x16x32(aF[0], bF, acc[0][n]);
      acc[1][n] = MFMA_16x16x32(aF[1], bF, acc[1][n]);
    }
  }
  // softmax over 150 valid cols; lane holds cols lr+16n of rows lg*4+r(+m*16)
  const float scale = 0.0625f;  // 1/sqrt(256)
#pragma unroll
  for (int m = 0; m < 2; m++) {
#pragma unroll
    for (int r = 0; r < 4; r++) {
      float lm = -1e30f;
#pragma unroll
      for (int n = 0; n < 10; n++) {
        float v = acc[m][n][r] * scale;
        acc[m][n][r] = v;
        if (n * 16 + lr < 150) lm = fmaxf(lm, v);
      }
#pragma unroll
      for (int msk = 1; msk <= 8; msk <<= 1) lm = fmaxf(lm, __shfl_xor(lm, msk, 64));
      float s = 0.f;
#pragma unroll
      for (int n = 0; n < 10; n++) {
        float p = (n * 16 + lr < 150) ? __expf(acc[m][n][r] - lm) : 0.f;
        acc[m][n][r] = p;
        s += p;
      }
#pragma unroll
      for (int msk = 1; msk <= 8; msk <<= 1) s += __shfl_xor(s, msk, 64);
      float inv = 1.f / s;
      const int row = w * 32 + m * 16 + lg * 4 + r;
#pragma unroll
      for (int n = 0; n < 10; n++)
        Pls[row * 168 + n * 16 + lr] = f2bf(acc[m][n][r] * inv);
    }
  }
  __syncthreads();
  // ctx = P @ V : M=128 pix, N=256 ch, K=160
  f32x4 acc2[2][16];
#pragma unroll
  for (int m = 0; m < 2; m++)
#pragma unroll
    for (int n = 0; n < 16; n++) acc2[m][n] = zero;
  for (int ks = 0; ks < 5; ks++) {
    bf16x8 aP[2];
#pragma unroll
    for (int m = 0; m < 2; m++)
      aP[m] = *(const bf16x8*)((const unsigned short*)Pls + (w * 32 + m * 16 + lr) * 168 + ks * 32 + lg * 8);
#pragma unroll
    for (int n = 0; n < 16; n++) {
      bf16x8 bV = *(const bf16x8*)(Vb + (size_t)(n * 16 + lr) * 160 + ks * 32 + lg * 8);
      acc2[0][n] = MFMA_16x16x32(aP[0], bV, acc2[0][n]);
      acc2[1][n] = MFMA_16x16x32(aP[1], bV, acc2[1][n]);
    }
  }
  unsigned short* Cb = ctxT + ((size_t)b * HW + pix0 + w * 32) * 256;
#pragma unroll
  for (int m = 0; m < 2; m++)
#pragma unroll
    for (int n = 0; n < 16; n++)
#pragma unroll
      for (int r = 0; r < 4; r++)
        Cb[(size_t)(m * 16 + lg * 4 + r) * 256 + n * 16 + lr] = f2bf(acc2[m][n][r]);
}

// ---------------- host launcher ----------------
extern "C" void kernel_launch(void* const* d_in, const int* in_sizes, int n_in,
                              void* d_out, int out_size, void* d_ws, size_t ws_size,
                              hipStream_t stream) {
  (void)in_sizes; (void)n_in; (void)out_size;
  const float* x     = (const float*)d_in[0];
  const float* proxy = (const float*)d_in[1];
  const float* w_fp1 = (const float*)d_in[2];
  const float* b_fp1 = (const float*)d_in[3];
  const float* w_fp2 = (const float*)d_in[4];
  const float* b_fp2 = (const float*)d_in[5];
  const float* w_fo1 = (const float*)d_in[6];
  const float* b_fo1 = (const float*)d_in[7];
  const float* w_fo2 = (const float*)d_in[8];
  const float* b_fo2 = (const float*)d_in[9];
  const float* w_fd  = (const float*)d_in[10];
  const float* b_fd  = (const float*)d_in[11];
  const float* w_fu  = (const float*)d_in[12];
  const float* b_fu  = (const float*)d_in[13];

  // workspace layout (bytes)
  char* ws = (char*)d_ws;
  unsigned short* W1b  = (unsigned short*)(ws + 0);          // 256x512 bf16
  unsigned short* W2b  = (unsigned short*)(ws + 262144);     // 256x256
  unsigned short* Wub  = (unsigned short*)(ws + 393216);     // 512x256
  unsigned short* keyT = (unsigned short*)(ws + 655360);     // [8][160][256]
  unsigned short* Vv   = (unsigned short*)(ws + 1310720);    // [8][256][160]
  unsigned short* bufA = (unsigned short*)(ws + 2097152);    // xT [8][16384][512], later q2T
  unsigned short* bufB = (unsigned short*)(ws + 2097152 + 134217728);  // q1T, later ctxT
  if (ws_size < 203423744) return;  // graceful fail if scratch too small

  dim3 blk(256);
  cast_f32_bf16<<<512, blk, 0, stream>>>(w_fp1, W1b, 131072);
  cast_f32_bf16<<<256, blk, 0, stream>>>(w_fp2, W2b, 65536);
  cast_f32_bf16<<<512, blk, 0, stream>>>(w_fu, Wub, 131072);
  transpose_cast_x<<<dim3(256, 8, 8), blk, 0, stream>>>(x, bufA);
  kv_kernel<<<dim3(20, 8), blk, 0, stream>>>(proxy, w_fo1, b_fo1, w_fo2, b_fo2,
                                             w_fd, b_fd, keyT, Vv);
  // q1T = relu(xT @ W1^T + b1)   [16384][256] per batch, bf16 out
  gemm_bt_relu<0, 0><<<dim3(128, 2, 8), blk, 0, stream>>>(
      bufA, W1b, b_fp1, bufB, 16384, 256, 512,
      (long long)16384 * 512, 0, (long long)16384 * 256);
  // q2T = relu(q1T @ W2^T + b2) -> bufA (xT dead), bf16 out
  gemm_bt_relu<0, 0><<<dim3(128, 2, 8), blk, 0, stream>>>(
      bufB, W2b, b_fp2, bufA, 16384, 256, 256,
      (long long)16384 * 256, 0, (long long)16384 * 256);
  // ctxT = softmax(q2T keyT^T / 16) @ V -> bufB (q1T dead)
  attn_kernel<<<dim3(128, 8), blk, 0, stream>>>(bufA, keyT, Vv, bufB);
  // out[co][pix] = relu(Wu @ ctxT^T + bu)  (channels-first), FP32 OUTPUT
  gemm_bt_relu<1, 1><<<dim3(4, 128, 8), blk, 0, stream>>>(
      Wub, bufB, b_fu, d_out, 512, 16384, 256,
      0, (long long)16384 * 256, (long long)512 * 16384);
}

// Round 4
// 428.744 us; speedup vs baseline: 1.1979x; 1.1979x over previous
//
#include <hip/hip_runtime.h>
#include <hip/hip_bf16.h>

// ObjectAttentionBlock on MI355X, round 4.
// r3 passed at 513.6us. attn_kernel (157us) was occupancy-bound: LDS 43008B
// -> 3 blocks/CU but grid needs 4/CU -> two scheduling rounds. Fix: P-buffer
// stride 168->160 (LDS 40960, 4 blocks/CU exactly) with XOR bank-swizzle,
// VGPR<=128 via __launch_bounds__(256,4) + PV split into two N-halves.
// GEMMs also get (256,4) for 4 blocks/CU (was 3 at VGPR=164).

typedef __bf16 bf16x8 __attribute__((ext_vector_type(8)));
typedef float f32x4 __attribute__((ext_vector_type(4)));
typedef unsigned short u16x8 __attribute__((ext_vector_type(8)));

#define MFMA_16x16x32(a, b, c) __builtin_amdgcn_mfma_f32_16x16x32_bf16((a), (b), (c), 0, 0, 0)

__device__ __forceinline__ unsigned short f2bf(float f) {
  union { float f; unsigned u; } x; x.f = f;
  unsigned r = (x.u + 0x7FFFu + ((x.u >> 16) & 1u)) >> 16;  // RNE
  return (unsigned short)r;
}

// ---------------- elementwise cast (weights) ----------------
__global__ __launch_bounds__(256) void cast_f32_bf16(const float* __restrict__ s,
                                                     unsigned short* __restrict__ d, int n) {
  int i = blockIdx.x * 256 + threadIdx.x;
  if (i < n) d[i] = f2bf(s[i]);
}

// ---------------- transpose + cast: x [B][512][HW] f32 -> xT [B][HW][512] bf16 ----------------
__global__ __launch_bounds__(256) void transpose_cast_x(const float* __restrict__ x,
                                                        unsigned short* __restrict__ xT) {
  const int HW = 16384, C = 512;
  __shared__ float tile[64][65];
  const int b = blockIdx.z;
  const int p0 = blockIdx.x * 64, c0 = blockIdx.y * 64;
  const int t = threadIdx.x;
#pragma unroll
  for (int i = 0; i < 4; i++) {
    int chunk = t + i * 256;            // 0..1023 -> 64 rows x 16 float4
    int cl = chunk >> 4, q = chunk & 15;
    float4 v = *(const float4*)(x + ((size_t)b * C + c0 + cl) * HW + p0 + q * 4);
    tile[cl][q * 4 + 0] = v.x; tile[cl][q * 4 + 1] = v.y;
    tile[cl][q * 4 + 2] = v.z; tile[cl][q * 4 + 3] = v.w;
  }
  __syncthreads();
  {
    int pl = t >> 2, g = t & 3;         // 64 pixels x 4 ch-groups
    u16x8 o0, o1;
#pragma unroll
    for (int j = 0; j < 8; j++) {
      o0[j] = f2bf(tile[g * 16 + j][pl]);
      o1[j] = f2bf(tile[g * 16 + 8 + j][pl]);
    }
    unsigned short* dst = xT + ((size_t)b * HW + p0 + pl) * C + c0 + g * 16;
    *(u16x8*)dst = o0;
    *(u16x8*)(dst + 8) = o1;
  }
}

// ---------------- key/value kernel (fp32 math, tiny) ----------------
__global__ __launch_bounds__(256) void kv_kernel(
    const float* __restrict__ proxy,
    const float* __restrict__ w_fo1, const float* __restrict__ b_fo1,
    const float* __restrict__ w_fo2, const float* __restrict__ b_fo2,
    const float* __restrict__ w_fd, const float* __restrict__ b_fd,
    unsigned short* __restrict__ keyT, unsigned short* __restrict__ Vv) {
  __shared__ float cols[512][8];
  __shared__ float k1s[256][8];
  const int b = blockIdx.y;
  const int p0 = blockIdx.x * 8;      // 20 chunks cover p 0..159
  const int t = threadIdx.x;
#pragma unroll
  for (int i = 0; i < 8; i++) {
    int idx = t + i * 256;
    int c = idx >> 2, q = idx & 3;
    int p = p0 + q * 2;
    float2 v = make_float2(0.f, 0.f);
    if (p < 150) v = *(const float2*)(proxy + ((size_t)b * 512 + c) * 150 + p);
    cols[c][q * 2 + 0] = v.x;
    cols[c][q * 2 + 1] = v.y;
  }
  __syncthreads();
  float accV[8], accK[8];
  {
    float bv = b_fd[t], bk = b_fo1[t];
#pragma unroll
    for (int px = 0; px < 8; px++) { accV[px] = bv; accK[px] = bk; }
  }
#define KV_FMA(j, wv_, wk_)                                      \
  { float4 ca = *(const float4*)&cols[c + j][0];                 \
    float4 cb = *(const float4*)&cols[c + j][4];                 \
    accV[0] += wv_ * ca.x; accV[1] += wv_ * ca.y;                \
    accV[2] += wv_ * ca.z; accV[3] += wv_ * ca.w;                \
    accV[4] += wv_ * cb.x; accV[5] += wv_ * cb.y;                \
    accV[6] += wv_ * cb.z; accV[7] += wv_ * cb.w;                \
    accK[0] += wk_ * ca.x; accK[1] += wk_ * ca.y;                \
    accK[2] += wk_ * ca.z; accK[3] += wk_ * ca.w;                \
    accK[4] += wk_ * cb.x; accK[5] += wk_ * cb.y;                \
    accK[6] += wk_ * cb.z; accK[7] += wk_ * cb.w; }
  for (int c = 0; c < 512; c += 4) {
    float4 wv4 = *(const float4*)(w_fd + (size_t)t * 512 + c);
    float4 wk4 = *(const float4*)(w_fo1 + (size_t)t * 512 + c);
    KV_FMA(0, wv4.x, wk4.x)
    KV_FMA(1, wv4.y, wk4.y)
    KV_FMA(2, wv4.z, wk4.z)
    KV_FMA(3, wv4.w, wk4.w)
  }
#pragma unroll
  for (int px = 0; px < 8; px++) {
    Vv[((size_t)b * 256 + t) * 160 + p0 + px] = f2bf(fmaxf(accV[px], 0.f));
    k1s[t][px] = fmaxf(accK[px], 0.f);
  }
  __syncthreads();
  float accY[8];
  {
    float by = b_fo2[t];
#pragma unroll
    for (int px = 0; px < 8; px++) accY[px] = by;
  }
#define KV_FMA2(j, wy_)                                          \
  { float4 ca = *(const float4*)&k1s[c + j][0];                  \
    float4 cb = *(const float4*)&k1s[c + j][4];                  \
    accY[0] += wy_ * ca.x; accY[1] += wy_ * ca.y;                \
    accY[2] += wy_ * ca.z; accY[3] += wy_ * ca.w;                \
    accY[4] += wy_ * cb.x; accY[5] += wy_ * cb.y;                \
    accY[6] += wy_ * cb.z; accY[7] += wy_ * cb.w; }
  for (int c = 0; c < 256; c += 4) {
    float4 wy4 = *(const float4*)(w_fo2 + (size_t)t * 256 + c);
    KV_FMA2(0, wy4.x)
    KV_FMA2(1, wy4.y)
    KV_FMA2(2, wy4.z)
    KV_FMA2(3, wy4.w)
  }
#pragma unroll
  for (int px = 0; px < 8; px++)
    keyT[((size_t)b * 160 + p0 + px) * 256 + t] = f2bf(fmaxf(accY[px], 0.f));
}

// ---------------- generic bf16 GEMM: C = relu(A @ Bt^T + bias) ----------------
template <int BIAS_ROW, int OUTF32>
__global__ __launch_bounds__(256, 4) void gemm_bt_relu(
    const unsigned short* __restrict__ A, const unsigned short* __restrict__ Bt,
    const float* __restrict__ bias, void* __restrict__ Cout,
    int M, int N, int K, long long sA, long long sB, long long sC) {
  __shared__ unsigned short As[128 * 64];
  __shared__ unsigned short Bs[128 * 64];
  const int b = blockIdx.z;
  const int m0 = blockIdx.x * 128, n0 = blockIdx.y * 128;
  const int tid = threadIdx.x;
  const int w = tid >> 6, l = tid & 63;
  const int lr = l & 15, lg = l >> 4;
  const int wm = (w >> 1) * 64, wn = (w & 1) * 64;
  const unsigned short* Ab = A + (size_t)b * sA + (size_t)m0 * K;
  const unsigned short* Btb = Bt + (size_t)b * sB + (size_t)n0 * K;
  const f32x4 zero = {0.f, 0.f, 0.f, 0.f};
  f32x4 acc[4][4];
#pragma unroll
  for (int m = 0; m < 4; m++)
#pragma unroll
    for (int n = 0; n < 4; n++) acc[m][n] = zero;

  const int srow = w * 32 + (l >> 3);   // staging row per lane
  const int scol = (l & 7) * 8;         // staging col (bf16 elems)
  for (int kt = 0; kt < K; kt += 64) {
    __syncthreads();
#pragma unroll
    for (int i = 0; i < 4; i++) {
      __builtin_amdgcn_global_load_lds(
          (__attribute__((address_space(1))) void*)(Ab + (size_t)(srow + i * 8) * K + kt + scol),
          (__attribute__((address_space(3))) void*)(As + (w * 32 + i * 8) * 64), 16, 0, 0);
      __builtin_amdgcn_global_load_lds(
          (__attribute__((address_space(1))) void*)(Btb + (size_t)(srow + i * 8) * K + kt + scol),
          (__attribute__((address_space(3))) void*)(Bs + (w * 32 + i * 8) * 64), 16, 0, 0);
    }
    __syncthreads();
#pragma unroll
    for (int ks = 0; ks < 2; ks++) {
      bf16x8 aF[4], bF[4];
#pragma unroll
      for (int m = 0; m < 4; m++)
        aF[m] = *(const bf16x8*)(As + (wm + m * 16 + lr) * 64 + ks * 32 + lg * 8);
#pragma unroll
      for (int n = 0; n < 4; n++)
        bF[n] = *(const bf16x8*)(Bs + (wn + n * 16 + lr) * 64 + ks * 32 + lg * 8);
#pragma unroll
      for (int m = 0; m < 4; m++)
#pragma unroll
        for (int n = 0; n < 4; n++) acc[m][n] = MFMA_16x16x32(aF[m], bF[n], acc[m][n]);
    }
  }
#pragma unroll
  for (int m = 0; m < 4; m++) {
#pragma unroll
    for (int n = 0; n < 4; n++) {
      const int col = n0 + wn + n * 16 + lr;
      const float bc = BIAS_ROW ? 0.f : bias[col];
#pragma unroll
      for (int r = 0; r < 4; r++) {
        const int row = m0 + wm + m * 16 + lg * 4 + r;
        float v = acc[m][n][r] + (BIAS_ROW ? bias[row] : bc);
        v = fmaxf(v, 0.f);
        if (OUTF32)
          ((float*)Cout)[(size_t)b * sC + (size_t)row * N + col] = v;
        else
          ((unsigned short*)Cout)[(size_t)b * sC + (size_t)row * N + col] = f2bf(v);
      }
    }
  }
}

// ---------------- fused attention: ctxT = softmax(Q Kt^T /16) @ V ----------------
// LDS: P buffer 128 rows x 160 cols bf16, stride 160 (40960B -> 4 blocks/CU).
// XOR swizzle byte^((row&7)<<4) applied on both write and read (G4).
__global__ __launch_bounds__(256, 4) void attn_kernel(
    const unsigned short* __restrict__ Q, const unsigned short* __restrict__ Kt,
    const unsigned short* __restrict__ Vv, unsigned short* __restrict__ ctxT) {
  const int HW = 16384;
  __shared__ unsigned short Pls[128 * 160];
  const int b = blockIdx.y;
  const int pix0 = blockIdx.x * 128;
  const int tid = threadIdx.x;
  const int w = tid >> 6, l = tid & 63;
  const int lr = l & 15, lg = l >> 4;
  const unsigned short* Qb = Q + ((size_t)b * HW + pix0 + w * 32) * 256;
  const unsigned short* Kb = Kt + (size_t)b * 160 * 256;
  const unsigned short* Vb = Vv + (size_t)b * 256 * 160;
  const f32x4 zero = {0.f, 0.f, 0.f, 0.f};

  // S = Q @ K^T : wave owns 32 pixel-rows x 160 key-cols
  f32x4 acc[2][10];
#pragma unroll
  for (int m = 0; m < 2; m++)
#pragma unroll
    for (int n = 0; n < 10; n++) acc[m][n] = zero;
#pragma unroll 2
  for (int ks = 0; ks < 8; ks++) {
    bf16x8 aF[2];
#pragma unroll
    for (int m = 0; m < 2; m++)
      aF[m] = *(const bf16x8*)(Qb + (size_t)(m * 16 + lr) * 256 + ks * 32 + lg * 8);
#pragma unroll
    for (int n = 0; n < 10; n++) {
      bf16x8 bF = *(const bf16x8*)(Kb + (size_t)(n * 16 + lr) * 256 + ks * 32 + lg * 8);
      acc[0][n] = MFMA_16x16x32(aF[0], bF, acc[0][n]);
      acc[1][n] = MFMA_16x16x32(aF[1], bF, acc[1][n]);
    }
  }
  // softmax over 150 valid cols; row's values live in 16 lanes (fixed lg)
  const float scale = 0.0625f;  // 1/sqrt(256)
#pragma unroll
  for (int m = 0; m < 2; m++) {
#pragma unroll
    for (int r = 0; r < 4; r++) {
      float lm = -1e30f;
#pragma unroll
      for (int n = 0; n < 10; n++) {
        float v = acc[m][n][r] * scale;
        acc[m][n][r] = v;
        if (n * 16 + lr < 150) lm = fmaxf(lm, v);
      }
#pragma unroll
      for (int msk = 1; msk <= 8; msk <<= 1) lm = fmaxf(lm, __shfl_xor(lm, msk, 64));
      float s = 0.f;
#pragma unroll
      for (int n = 0; n < 10; n++) {
        float p = (n * 16 + lr < 150) ? __expf(acc[m][n][r] - lm) : 0.f;
        acc[m][n][r] = p;
        s += p;
      }
#pragma unroll
      for (int msk = 1; msk <= 8; msk <<= 1) s += __shfl_xor(s, msk, 64);
      float inv = 1.f / s;
      const int row = w * 32 + m * 16 + lg * 4 + r;
      const unsigned sw = (unsigned)(row & 7) << 4;
#pragma unroll
      for (int n = 0; n < 10; n++) {
        unsigned boff = (unsigned)row * 320 + (unsigned)(n * 16 + lr) * 2;
        *(unsigned short*)((char*)Pls + (boff ^ sw)) = f2bf(acc[m][n][r] * inv);
      }
    }
  }
  __syncthreads();
  // ctx = P @ V : M=128 pix, K=160; N=256 split into two halves of 128
  unsigned short* Cb = ctxT + ((size_t)b * HW + pix0 + w * 32) * 256;
#pragma unroll
  for (int half = 0; half < 2; half++) {
    f32x4 acc2[2][8];
#pragma unroll
    for (int m = 0; m < 2; m++)
#pragma unroll
      for (int n = 0; n < 8; n++) acc2[m][n] = zero;
    for (int ks = 0; ks < 5; ks++) {
      bf16x8 aP[2];
#pragma unroll
      for (int m = 0; m < 2; m++) {
        const int row = w * 32 + m * 16 + lr;
        unsigned boff = (unsigned)row * 320 + (unsigned)(ks * 64 + lg * 16);
        aP[m] = *(const bf16x8*)((const char*)Pls + (boff ^ ((unsigned)(row & 7) << 4)));
      }
#pragma unroll
      for (int n = 0; n < 8; n++) {
        const int ch = half * 128 + n * 16 + lr;
        bf16x8 bV = *(const bf16x8*)(Vb + (size_t)ch * 160 + ks * 32 + lg * 8);
        acc2[0][n] = MFMA_16x16x32(aP[0], bV, acc2[0][n]);
        acc2[1][n] = MFMA_16x16x32(aP[1], bV, acc2[1][n]);
      }
    }
#pragma unroll
    for (int m = 0; m < 2; m++)
#pragma unroll
      for (int n = 0; n < 8; n++)
#pragma unroll
        for (int r = 0; r < 4; r++)
          Cb[(size_t)(m * 16 + lg * 4 + r) * 256 + half * 128 + n * 16 + lr] =
              f2bf(acc2[m][n][r]);
  }
}

// ---------------- host launcher ----------------
extern "C" void kernel_launch(void* const* d_in, const int* in_sizes, int n_in,
                              void* d_out, int out_size, void* d_ws, size_t ws_size,
                              hipStream_t stream) {
  (void)in_sizes; (void)n_in; (void)out_size;
  const float* x     = (const float*)d_in[0];
  const float* proxy = (const float*)d_in[1];
  const float* w_fp1 = (const float*)d_in[2];
  const float* b_fp1 = (const float*)d_in[3];
  const float* w_fp2 = (const float*)d_in[4];
  const float* b_fp2 = (const float*)d_in[5];
  const float* w_fo1 = (const float*)d_in[6];
  const float* b_fo1 = (const float*)d_in[7];
  const float* w_fo2 = (const float*)d_in[8];
  const float* b_fo2 = (const float*)d_in[9];
  const float* w_fd  = (const float*)d_in[10];
  const float* b_fd  = (const float*)d_in[11];
  const float* w_fu  = (const float*)d_in[12];
  const float* b_fu  = (const float*)d_in[13];

  // workspace layout (bytes)
  char* ws = (char*)d_ws;
  unsigned short* W1b  = (unsigned short*)(ws + 0);          // 256x512 bf16
  unsigned short* W2b  = (unsigned short*)(ws + 262144);     // 256x256
  unsigned short* Wub  = (unsigned short*)(ws + 393216);     // 512x256
  unsigned short* keyT = (unsigned short*)(ws + 655360);     // [8][160][256]
  unsigned short* Vv   = (unsigned short*)(ws + 1310720);    // [8][256][160]
  unsigned short* bufA = (unsigned short*)(ws + 2097152);    // xT, later q2T
  unsigned short* bufB = (unsigned short*)(ws + 2097152 + 134217728);  // q1T, later ctxT
  if (ws_size < 203423744) return;

  dim3 blk(256);
  cast_f32_bf16<<<512, blk, 0, stream>>>(w_fp1, W1b, 131072);
  cast_f32_bf16<<<256, blk, 0, stream>>>(w_fp2, W2b, 65536);
  cast_f32_bf16<<<512, blk, 0, stream>>>(w_fu, Wub, 131072);
  transpose_cast_x<<<dim3(256, 8, 8), blk, 0, stream>>>(x, bufA);
  kv_kernel<<<dim3(20, 8), blk, 0, stream>>>(proxy, w_fo1, b_fo1, w_fo2, b_fo2,
                                             w_fd, b_fd, keyT, Vv);
  // q1T = relu(xT @ W1^T + b1)
  gemm_bt_relu<0, 0><<<dim3(128, 2, 8), blk, 0, stream>>>(
      bufA, W1b, b_fp1, bufB, 16384, 256, 512,
      (long long)16384 * 512, 0, (long long)16384 * 256);
  // q2T = relu(q1T @ W2^T + b2) -> bufA
  gemm_bt_relu<0, 0><<<dim3(128, 2, 8), blk, 0, stream>>>(
      bufB, W2b, b_fp2, bufA, 16384, 256, 256,
      (long long)16384 * 256, 0, (long long)16384 * 256);
  // ctxT = softmax(q2T keyT^T / 16) @ V -> bufB
  attn_kernel<<<dim3(128, 8), blk, 0, stream>>>(bufA, keyT, Vv, bufB);
  // out[co][pix] = relu(Wu @ ctxT^T + bu), FP32 output
  gemm_bt_relu<1, 1><<<dim3(4, 128, 8), blk, 0, stream>>>(
      Wub, bufB, b_fu, d_out, 512, 16384, 256,
      0, (long long)16384 * 256, (long long)512 * 16384);
}

// Round 5
// 377.183 us; speedup vs baseline: 1.3617x; 1.1367x over previous
//
#include <hip/hip_runtime.h>
#include <hip/hip_bf16.h>

// ObjectAttentionBlock on MI355X, round 5.
// vs r4 (428.7us): delete the standalone x-transpose pass (~70us, 384MB) by
// fusing transpose+cast into GEMM1's staging: f32 x tile staged linearly via
// global_load_lds with XOR-pre-swizzled SOURCE columns (rule #21), A-frags
// built by transposed ds_read_b32 column reads + cvt to bf16 (k-order matches
// B-frag so the lane->k permutation cancels as before). XCD-pair remap puts
// the two n-blocks sharing an A-tile on the same XCD. 3 weight casts merged.

typedef __bf16 bf16x8 __attribute__((ext_vector_type(8)));
typedef float f32x4 __attribute__((ext_vector_type(4)));
typedef unsigned short u16x8 __attribute__((ext_vector_type(8)));

#define AS1 __attribute__((address_space(1)))
#define AS3 __attribute__((address_space(3)))
#define MFMA_16x16x32(a, b, c) __builtin_amdgcn_mfma_f32_16x16x32_bf16((a), (b), (c), 0, 0, 0)

__device__ __forceinline__ unsigned short f2bf(float f) {
  union { float f; unsigned u; } x; x.f = f;
  unsigned r = (x.u + 0x7FFFu + ((x.u >> 16) & 1u)) >> 16;  // RNE
  return (unsigned short)r;
}

// ---------------- merged weight cast ----------------
__global__ __launch_bounds__(256) void cast_weights(
    const float* __restrict__ w1, const float* __restrict__ w2,
    const float* __restrict__ wu, unsigned short* __restrict__ W1b,
    unsigned short* __restrict__ W2b, unsigned short* __restrict__ Wub) {
  int i = blockIdx.x * 256 + threadIdx.x;   // grid 1280 -> 327680 items
  if (i < 131072) W1b[i] = f2bf(w1[i]);
  else if (i < 196608) W2b[i - 131072] = f2bf(w2[i - 131072]);
  else if (i < 327680) Wub[i - 196608] = f2bf(wu[i - 196608]);
}

// ---------------- key/value kernel (fp32 math, tiny) ----------------
__global__ __launch_bounds__(256) void kv_kernel(
    const float* __restrict__ proxy,
    const float* __restrict__ w_fo1, const float* __restrict__ b_fo1,
    const float* __restrict__ w_fo2, const float* __restrict__ b_fo2,
    const float* __restrict__ w_fd, const float* __restrict__ b_fd,
    unsigned short* __restrict__ keyT, unsigned short* __restrict__ Vv) {
  __shared__ float cols[512][8];
  __shared__ float k1s[256][8];
  const int b = blockIdx.y;
  const int p0 = blockIdx.x * 8;      // 20 chunks cover p 0..159
  const int t = threadIdx.x;
#pragma unroll
  for (int i = 0; i < 8; i++) {
    int idx = t + i * 256;
    int c = idx >> 2, q = idx & 3;
    int p = p0 + q * 2;
    float2 v = make_float2(0.f, 0.f);
    if (p < 150) v = *(const float2*)(proxy + ((size_t)b * 512 + c) * 150 + p);
    cols[c][q * 2 + 0] = v.x;
    cols[c][q * 2 + 1] = v.y;
  }
  __syncthreads();
  float accV[8], accK[8];
  {
    float bv = b_fd[t], bk = b_fo1[t];
#pragma unroll
    for (int px = 0; px < 8; px++) { accV[px] = bv; accK[px] = bk; }
  }
#define KV_FMA(j, wv_, wk_)                                      \
  { float4 ca = *(const float4*)&cols[c + j][0];                 \
    float4 cb = *(const float4*)&cols[c + j][4];                 \
    accV[0] += wv_ * ca.x; accV[1] += wv_ * ca.y;                \
    accV[2] += wv_ * ca.z; accV[3] += wv_ * ca.w;                \
    accV[4] += wv_ * cb.x; accV[5] += wv_ * cb.y;                \
    accV[6] += wv_ * cb.z; accV[7] += wv_ * cb.w;                \
    accK[0] += wk_ * ca.x; accK[1] += wk_ * ca.y;                \
    accK[2] += wk_ * ca.z; accK[3] += wk_ * ca.w;                \
    accK[4] += wk_ * cb.x; accK[5] += wk_ * cb.y;                \
    accK[6] += wk_ * cb.z; accK[7] += wk_ * cb.w; }
  for (int c = 0; c < 512; c += 4) {
    float4 wv4 = *(const float4*)(w_fd + (size_t)t * 512 + c);
    float4 wk4 = *(const float4*)(w_fo1 + (size_t)t * 512 + c);
    KV_FMA(0, wv4.x, wk4.x)
    KV_FMA(1, wv4.y, wk4.y)
    KV_FMA(2, wv4.z, wk4.z)
    KV_FMA(3, wv4.w, wk4.w)
  }
#pragma unroll
  for (int px = 0; px < 8; px++) {
    Vv[((size_t)b * 256 + t) * 160 + p0 + px] = f2bf(fmaxf(accV[px], 0.f));
    k1s[t][px] = fmaxf(accK[px], 0.f);
  }
  __syncthreads();
  float accY[8];
  {
    float by = b_fo2[t];
#pragma unroll
    for (int px = 0; px < 8; px++) accY[px] = by;
  }
#define KV_FMA2(j, wy_)                                          \
  { float4 ca = *(const float4*)&k1s[c + j][0];                  \
    float4 cb = *(const float4*)&k1s[c + j][4];                  \
    accY[0] += wy_ * ca.x; accY[1] += wy_ * ca.y;                \
    accY[2] += wy_ * ca.z; accY[3] += wy_ * ca.w;                \
    accY[4] += wy_ * cb.x; accY[5] += wy_ * cb.y;                \
    accY[6] += wy_ * cb.z; accY[7] += wy_ * cb.w; }
  for (int c = 0; c < 256; c += 4) {
    float4 wy4 = *(const float4*)(w_fo2 + (size_t)t * 256 + c);
    KV_FMA2(0, wy4.x)
    KV_FMA2(1, wy4.y)
    KV_FMA2(2, wy4.z)
    KV_FMA2(3, wy4.w)
  }
#pragma unroll
  for (int px = 0; px < 8; px++)
    keyT[((size_t)b * 160 + p0 + px) * 256 + t] = f2bf(fmaxf(accY[px], 0.f));
}

// ---------------- GEMM1 fused transpose: q1T = relu(x^T @ W1^T + b1) ----------------
// X [B][512][16384] f32 (channel-major). A-tile x[kt..kt+64][p0..p0+128] staged
// as f32 LDS [64][128] with source-col XOR swizzle: Af[rk][c] holds
// x[kt+rk][p0 + ((c>>2)^s)*4 + (c&3)], s=(rk>>3)&7. A-frag for pixel p, k=rk
// reads Af byte rk*512 + ((((p>>2)^s)<<2 | (p&3))<<2). Swizzle makes frag
// column reads <=4-way bank conflicts (hidden under HBM).
__global__ __launch_bounds__(256, 3) void gemm1_fused(
    const float* __restrict__ X, const unsigned short* __restrict__ Bt,
    const float* __restrict__ bias, unsigned short* __restrict__ Cq) {
  const int HW = 16384, K = 512, N = 256;
  __shared__ float Af[64 * 128];
  __shared__ unsigned short Bs[128 * 64];
  // XCD-pair remap: pair (nx=0,1) of same my lands on same XCD (flat%8), 8 apart
  const int r = blockIdx.x;                 // 0..255
  const int b = blockIdx.y;
  const int my = ((r >> 4) << 3) | (r & 7); // 0..127
  const int nx = (r >> 3) & 1;
  const int m0 = my * 128, n0 = nx * 128;
  const int tid = threadIdx.x;
  const int w = tid >> 6, l = tid & 63;
  const int lr = l & 15, lg = l >> 4;
  const int wm = (w >> 1) * 64, wn = (w & 1) * 64;
  const float* Xb = X + (size_t)b * K * HW;
  const unsigned short* Btb = Bt + (size_t)n0 * K;
  const f32x4 zero = {0.f, 0.f, 0.f, 0.f};
  f32x4 acc[4][4];
#pragma unroll
  for (int m = 0; m < 4; m++)
#pragma unroll
    for (int n = 0; n < 4; n++) acc[m][n] = zero;

  const int arow = l >> 5;                  // 0..1 within op
  const int acol = l & 31;                  // f32-quad index within row
  const int bsub = l >> 3;                  // B staging row-within-8
  const int bcol = (l & 7) * 8;             // B staging col (bf16)
  for (int kt = 0; kt < K; kt += 64) {
    __syncthreads();
    // A: 8 ops/wave, 2 rows each; source col pre-swizzled
#pragma unroll
    for (int i = 0; i < 8; i++) {
      const int rk = w * 16 + i * 2 + arow;          // tile k-row 0..63
      const int s = (rk >> 3) & 7;
      __builtin_amdgcn_global_load_lds(
          (AS1 void*)(Xb + (size_t)(kt + rk) * HW + m0 + ((acol ^ s) << 2)),
          (AS3 void*)(Af + (w * 16 + i * 2) * 128), 16, 0, 0);
    }
    // B: 4 ops/wave (unchanged pattern)
#pragma unroll
    for (int i = 0; i < 4; i++) {
      __builtin_amdgcn_global_load_lds(
          (AS1 void*)(Btb + (size_t)(w * 32 + i * 8 + bsub) * K + kt + bcol),
          (AS3 void*)(Bs + (w * 32 + i * 8) * 64), 16, 0, 0);
    }
    __syncthreads();
#pragma unroll
    for (int ks = 0; ks < 2; ks++) {
      bf16x8 aF[4], bF[4];
      const int s = ks * 4 + lg;            // (rk>>3)&7 for rk=ks*32+lg*8+j
#pragma unroll
      for (int m = 0; m < 4; m++) {
        const int p = wm + m * 16 + lr;
        const int cb = ((((p >> 2) ^ s) << 2) | (p & 3));
        bf16x8 a;
#pragma unroll
        for (int j = 0; j < 8; j++)
          a[j] = (__bf16)Af[(ks * 32 + lg * 8 + j) * 128 + cb];
        aF[m] = a;
      }
#pragma unroll
      for (int n = 0; n < 4; n++)
        bF[n] = *(const bf16x8*)(Bs + (wn + n * 16 + lr) * 64 + ks * 32 + lg * 8);
#pragma unroll
      for (int m = 0; m < 4; m++)
#pragma unroll
        for (int n = 0; n < 4; n++) acc[m][n] = MFMA_16x16x32(aF[m], bF[n], acc[m][n]);
    }
  }
  unsigned short* Cb = Cq + (size_t)b * HW * N;
#pragma unroll
  for (int m = 0; m < 4; m++) {
#pragma unroll
    for (int n = 0; n < 4; n++) {
      const int col = n0 + wn + n * 16 + lr;
      const float bc = bias[col];
#pragma unroll
      for (int r2 = 0; r2 < 4; r2++) {
        const int row = m0 + wm + m * 16 + lg * 4 + r2;
        Cb[(size_t)row * N + col] = f2bf(fmaxf(acc[m][n][r2] + bc, 0.f));
      }
    }
  }
}

// ---------------- generic bf16 GEMM: C = relu(A @ Bt^T + bias) ----------------
template <int BIAS_ROW, int OUTF32>
__global__ __launch_bounds__(256, 4) void gemm_bt_relu(
    const unsigned short* __restrict__ A, const unsigned short* __restrict__ Bt,
    const float* __restrict__ bias, void* __restrict__ Cout,
    int M, int N, int K, long long sA, long long sB, long long sC) {
  __shared__ unsigned short As[128 * 64];
  __shared__ unsigned short Bs[128 * 64];
  const int b = blockIdx.z;
  const int m0 = blockIdx.x * 128, n0 = blockIdx.y * 128;
  const int tid = threadIdx.x;
  const int w = tid >> 6, l = tid & 63;
  const int lr = l & 15, lg = l >> 4;
  const int wm = (w >> 1) * 64, wn = (w & 1) * 64;
  const unsigned short* Ab = A + (size_t)b * sA + (size_t)m0 * K;
  const unsigned short* Btb = Bt + (size_t)b * sB + (size_t)n0 * K;
  const f32x4 zero = {0.f, 0.f, 0.f, 0.f};
  f32x4 acc[4][4];
#pragma unroll
  for (int m = 0; m < 4; m++)
#pragma unroll
    for (int n = 0; n < 4; n++) acc[m][n] = zero;

  const int srow = w * 32 + (l >> 3);
  const int scol = (l & 7) * 8;
  for (int kt = 0; kt < K; kt += 64) {
    __syncthreads();
#pragma unroll
    for (int i = 0; i < 4; i++) {
      __builtin_amdgcn_global_load_lds(
          (AS1 void*)(Ab + (size_t)(srow + i * 8) * K + kt + scol),
          (AS3 void*)(As + (w * 32 + i * 8) * 64), 16, 0, 0);
      __builtin_amdgcn_global_load_lds(
          (AS1 void*)(Btb + (size_t)(srow + i * 8) * K + kt + scol),
          (AS3 void*)(Bs + (w * 32 + i * 8) * 64), 16, 0, 0);
    }
    __syncthreads();
#pragma unroll
    for (int ks = 0; ks < 2; ks++) {
      bf16x8 aF[4], bF[4];
#pragma unroll
      for (int m = 0; m < 4; m++)
        aF[m] = *(const bf16x8*)(As + (wm + m * 16 + lr) * 64 + ks * 32 + lg * 8);
#pragma unroll
      for (int n = 0; n < 4; n++)
        bF[n] = *(const bf16x8*)(Bs + (wn + n * 16 + lr) * 64 + ks * 32 + lg * 8);
#pragma unroll
      for (int m = 0; m < 4; m++)
#pragma unroll
        for (int n = 0; n < 4; n++) acc[m][n] = MFMA_16x16x32(aF[m], bF[n], acc[m][n]);
    }
  }
#pragma unroll
  for (int m = 0; m < 4; m++) {
#pragma unroll
    for (int n = 0; n < 4; n++) {
      const int col = n0 + wn + n * 16 + lr;
      const float bc = BIAS_ROW ? 0.f : bias[col];
#pragma unroll
      for (int r = 0; r < 4; r++) {
        const int row = m0 + wm + m * 16 + lg * 4 + r;
        float v = acc[m][n][r] + (BIAS_ROW ? bias[row] : bc);
        v = fmaxf(v, 0.f);
        if (OUTF32)
          ((float*)Cout)[(size_t)b * sC + (size_t)row * N + col] = v;
        else
          ((unsigned short*)Cout)[(size_t)b * sC + (size_t)row * N + col] = f2bf(v);
      }
    }
  }
}

// ---------------- fused attention: ctxT = softmax(Q Kt^T /16) @ V ----------------
__global__ __launch_bounds__(256, 4) void attn_kernel(
    const unsigned short* __restrict__ Q, const unsigned short* __restrict__ Kt,
    const unsigned short* __restrict__ Vv, unsigned short* __restrict__ ctxT) {
  const int HW = 16384;
  __shared__ unsigned short Pls[128 * 160];
  const int b = blockIdx.y;
  const int pix0 = blockIdx.x * 128;
  const int tid = threadIdx.x;
  const int w = tid >> 6, l = tid & 63;
  const int lr = l & 15, lg = l >> 4;
  const unsigned short* Qb = Q + ((size_t)b * HW + pix0 + w * 32) * 256;
  const unsigned short* Kb = Kt + (size_t)b * 160 * 256;
  const unsigned short* Vb = Vv + (size_t)b * 256 * 160;
  const f32x4 zero = {0.f, 0.f, 0.f, 0.f};

  f32x4 acc[2][10];
#pragma unroll
  for (int m = 0; m < 2; m++)
#pragma unroll
    for (int n = 0; n < 10; n++) acc[m][n] = zero;
#pragma unroll 2
  for (int ks = 0; ks < 8; ks++) {
    bf16x8 aF[2];
#pragma unroll
    for (int m = 0; m < 2; m++)
      aF[m] = *(const bf16x8*)(Qb + (size_t)(m * 16 + lr) * 256 + ks * 32 + lg * 8);
#pragma unroll
    for (int n = 0; n < 10; n++) {
      bf16x8 bF = *(const bf16x8*)(Kb + (size_t)(n * 16 + lr) * 256 + ks * 32 + lg * 8);
      acc[0][n] = MFMA_16x16x32(aF[0], bF, acc[0][n]);
      acc[1][n] = MFMA_16x16x32(aF[1], bF, acc[1][n]);
    }
  }
  const float scale = 0.0625f;  // 1/sqrt(256)
#pragma unroll
  for (int m = 0; m < 2; m++) {
#pragma unroll
    for (int r = 0; r < 4; r++) {
      float lm = -1e30f;
#pragma unroll
      for (int n = 0; n < 10; n++) {
        float v = acc[m][n][r] * scale;
        acc[m][n][r] = v;
        if (n * 16 + lr < 150) lm = fmaxf(lm, v);
      }
#pragma unroll
      for (int msk = 1; msk <= 8; msk <<= 1) lm = fmaxf(lm, __shfl_xor(lm, msk, 64));
      float s = 0.f;
#pragma unroll
      for (int n = 0; n < 10; n++) {
        float p = (n * 16 + lr < 150) ? __expf(acc[m][n][r] - lm) : 0.f;
        acc[m][n][r] = p;
        s += p;
      }
#pragma unroll
      for (int msk = 1; msk <= 8; msk <<= 1) s += __shfl_xor(s, msk, 64);
      float inv = 1.f / s;
      const int row = w * 32 + m * 16 + lg * 4 + r;
      const unsigned sw = (unsigned)(row & 7) << 4;
#pragma unroll
      for (int n = 0; n < 10; n++) {
        unsigned boff = (unsigned)row * 320 + (unsigned)(n * 16 + lr) * 2;
        *(unsigned short*)((char*)Pls + (boff ^ sw)) = f2bf(acc[m][n][r] * inv);
      }
    }
  }
  __syncthreads();
  unsigned short* Cb = ctxT + ((size_t)b * HW + pix0 + w * 32) * 256;
#pragma unroll
  for (int half = 0; half < 2; half++) {
    f32x4 acc2[2][8];
#pragma unroll
    for (int m = 0; m < 2; m++)
#pragma unroll
      for (int n = 0; n < 8; n++) acc2[m][n] = zero;
    for (int ks = 0; ks < 5; ks++) {
      bf16x8 aP[2];
#pragma unroll
      for (int m = 0; m < 2; m++) {
        const int row = w * 32 + m * 16 + lr;
        unsigned boff = (unsigned)row * 320 + (unsigned)(ks * 64 + lg * 16);
        aP[m] = *(const bf16x8*)((const char*)Pls + (boff ^ ((unsigned)(row & 7) << 4)));
      }
#pragma unroll
      for (int n = 0; n < 8; n++) {
        const int ch = half * 128 + n * 16 + lr;
        bf16x8 bV = *(const bf16x8*)(Vb + (size_t)ch * 160 + ks * 32 + lg * 8);
        acc2[0][n] = MFMA_16x16x32(aP[0], bV, acc2[0][n]);
        acc2[1][n] = MFMA_16x16x32(aP[1], bV, acc2[1][n]);
      }
    }
#pragma unroll
    for (int m = 0; m < 2; m++)
#pragma unroll
      for (int n = 0; n < 8; n++)
#pragma unroll
        for (int r = 0; r < 4; r++)
          Cb[(size_t)(m * 16 + lg * 4 + r) * 256 + half * 128 + n * 16 + lr] =
              f2bf(acc2[m][n][r]);
  }
}

// ---------------- host launcher ----------------
extern "C" void kernel_launch(void* const* d_in, const int* in_sizes, int n_in,
                              void* d_out, int out_size, void* d_ws, size_t ws_size,
                              hipStream_t stream) {
  (void)in_sizes; (void)n_in; (void)out_size;
  const float* x     = (const float*)d_in[0];
  const float* proxy = (const float*)d_in[1];
  const float* w_fp1 = (const float*)d_in[2];
  const float* b_fp1 = (const float*)d_in[3];
  const float* w_fp2 = (const float*)d_in[4];
  const float* b_fp2 = (const float*)d_in[5];
  const float* w_fo1 = (const float*)d_in[6];
  const float* b_fo1 = (const float*)d_in[7];
  const float* w_fo2 = (const float*)d_in[8];
  const float* b_fo2 = (const float*)d_in[9];
  const float* w_fd  = (const float*)d_in[10];
  const float* b_fd  = (const float*)d_in[11];
  const float* w_fu  = (const float*)d_in[12];
  const float* b_fu  = (const float*)d_in[13];

  char* ws = (char*)d_ws;
  unsigned short* W1b  = (unsigned short*)(ws + 0);          // 256x512 bf16
  unsigned short* W2b  = (unsigned short*)(ws + 262144);     // 256x256
  unsigned short* Wub  = (unsigned short*)(ws + 393216);     // 512x256
  unsigned short* keyT = (unsigned short*)(ws + 655360);     // [8][160][256]
  unsigned short* Vv   = (unsigned short*)(ws + 1310720);    // [8][256][160]
  unsigned short* bufA = (unsigned short*)(ws + 2097152);    // q2T
  unsigned short* bufB = (unsigned short*)(ws + 2097152 + 134217728);  // q1T, later ctxT
  if (ws_size < 203423744) return;

  dim3 blk(256);
  cast_weights<<<1280, blk, 0, stream>>>(w_fp1, w_fp2, w_fu, W1b, W2b, Wub);
  kv_kernel<<<dim3(20, 8), blk, 0, stream>>>(proxy, w_fo1, b_fo1, w_fo2, b_fo2,
                                             w_fd, b_fd, keyT, Vv);
  // q1T = relu(x^T @ W1^T + b1) with fused transpose -> bufB
  gemm1_fused<<<dim3(256, 8), blk, 0, stream>>>(x, W1b, b_fp1, bufB);
  // q2T = relu(q1T @ W2^T + b2) -> bufA
  gemm_bt_relu<0, 0><<<dim3(128, 2, 8), blk, 0, stream>>>(
      bufB, W2b, b_fp2, bufA, 16384, 256, 256,
      (long long)16384 * 256, 0, (long long)16384 * 256);
  // ctxT = softmax(q2T keyT^T / 16) @ V -> bufB
  attn_kernel<<<dim3(128, 8), blk, 0, stream>>>(bufA, keyT, Vv, bufB);
  // out[co][pix] = relu(Wu @ ctxT^T + bu), FP32 output
  gemm_bt_relu<1, 1><<<dim3(4, 128, 8), blk, 0, stream>>>(
      Wub, bufB, b_fu, d_out, 512, 16384, 256,
      0, (long long)16384 * 256, (long long)512 * 16384);
}